// Round 3
// baseline (357.882 us; speedup 1.0000x reference)
//
#include <hip/hip_runtime.h>
#include <cstdint>
#include <cstddef>

#define HID 1024
#define SEQ 4096
#define NB  2
#define NH  16
#define HD  64
#define WIN 512
#define TOK (NB*SEQ)   // 8192 tokens

typedef _Float16 f16x8 __attribute__((ext_vector_type(8)));
typedef _Float16 f16x4 __attribute__((ext_vector_type(4)));
typedef float    f32x4 __attribute__((ext_vector_type(4)));

// ---------- fp32 -> fp16 conversion ----------
__global__ __launch_bounds__(256)
void convertX_kernel(const float* __restrict__ src, _Float16* __restrict__ dst) {
  const int i = (blockIdx.x * 256 + threadIdx.x) * 8;   // grid sized exactly
  f32x4 a = *(const f32x4*)(src + i);
  f32x4 b = *(const f32x4*)(src + i + 4);
  f16x8 o;
#pragma unroll
  for (int r = 0; r < 4; ++r) { o[r] = (_Float16)a[r]; o[r+4] = (_Float16)b[r]; }
  *(f16x8*)(dst + i) = o;
}

__global__ __launch_bounds__(256)
void convertW_kernel(const float* __restrict__ w0, const float* __restrict__ w1,
                     const float* __restrict__ w2, const float* __restrict__ w3,
                     _Float16* __restrict__ dst) {
  const int z = blockIdx.z;
  const float* s = (z == 0) ? w0 : (z == 1) ? w1 : (z == 2) ? w2 : w3;
  _Float16* d = dst + (size_t)z * HID * HID;
  const int i = (blockIdx.x * 256 + threadIdx.x) * 8;
  f32x4 a = *(const f32x4*)(s + i);
  f32x4 b = *(const f32x4*)(s + i + 4);
  f16x8 o;
#pragma unroll
  for (int r = 0; r < 4; ++r) { o[r] = (_Float16)a[r]; o[r+4] = (_Float16)b[r]; }
  *(f16x8*)(d + i) = o;
}

// ---------- C = A @ W^T main loop (fp16 in, fp32 acc) ----------
// A:[M,1024] f16 row-major, W:[N,1024] f16 row-major. 128x128 tile, BK=32,
// 4 waves x (64x64 via 4x4 grid of 16x16x32 MFMAs). Register staging.
__device__ __forceinline__ void gemm_mainloop(
    const _Float16* __restrict__ A, const _Float16* __restrict__ W,
    _Float16* sA, _Float16* sB, f32x4 (&acc)[4][4], int m0, int n0) {
  const int tid  = threadIdx.x;
  const int lane = tid & 63;
  const int wave = tid >> 6;
  const int wm = wave >> 1, wn = wave & 1;
  const int l15 = lane & 15, quad = lane >> 4;

  const int r0 = tid >> 2;            // 0..63
  const int c0 = (tid & 3) * 8;       // 0,8,16,24
  const _Float16* ga0 = A + (size_t)(m0 + r0)      * HID + c0;
  const _Float16* ga1 = A + (size_t)(m0 + r0 + 64) * HID + c0;
  const _Float16* gw0 = W + (size_t)(n0 + r0)      * HID + c0;
  const _Float16* gw1 = W + (size_t)(n0 + r0 + 64) * HID + c0;
  _Float16* la0 = sA + r0*32 + c0;
  _Float16* la1 = sA + (r0 + 64)*32 + c0;
  _Float16* lb0 = sB + r0*32 + c0;
  _Float16* lb1 = sB + (r0 + 64)*32 + c0;

  const int aoff = (wm*64 + l15)*32 + quad*8;   // + t*512 per 16-row subtile
  const int boff = (wn*64 + l15)*32 + quad*8;

  for (int k0 = 0; k0 < HID; k0 += 32) {
    f16x8 va0 = *(const f16x8*)(ga0 + k0);
    f16x8 va1 = *(const f16x8*)(ga1 + k0);
    f16x8 vw0 = *(const f16x8*)(gw0 + k0);
    f16x8 vw1 = *(const f16x8*)(gw1 + k0);
    __syncthreads();                 // WAR: prior iter's LDS reads done
    *(f16x8*)la0 = va0;
    *(f16x8*)la1 = va1;
    *(f16x8*)lb0 = vw0;
    *(f16x8*)lb1 = vw1;
    __syncthreads();                 // staging visible
    f16x8 af[4], wf[4];
#pragma unroll
    for (int t = 0; t < 4; ++t) {
      af[t] = *(const f16x8*)(sA + aoff + t*512);
      wf[t] = *(const f16x8*)(sB + boff + t*512);
    }
#pragma unroll
    for (int i = 0; i < 4; ++i)
#pragma unroll
      for (int j = 0; j < 4; ++j)
        acc[i][j] = __builtin_amdgcn_mfma_f32_16x16x32_f16(af[i], wf[j], acc[i][j], 0, 0, 0);
  }
}

// z=0: Q, z=1: K (row-major [token][1024] f16); z=2: V transposed Vt[feat][token]
__global__ __launch_bounds__(256, 2)
void gemm_qkv_kernel(const _Float16* __restrict__ X,
                     const _Float16* __restrict__ Wh,   // 4 weights concatenated
                     _Float16* __restrict__ Q,
                     _Float16* __restrict__ Kb,
                     _Float16* __restrict__ Vt) {
  __shared__ __align__(16) _Float16 sA[128*32];
  __shared__ __align__(16) _Float16 sB[128*32];
  const int z = blockIdx.z;
  const _Float16* W = Wh + (size_t)z * HID * HID;
  const int m0 = blockIdx.y * 128;
  const int n0 = blockIdx.x * 128;
  f32x4 acc[4][4] = {};
  gemm_mainloop(X, W, sA, sB, acc, m0, n0);

  const int tid  = threadIdx.x;
  const int lane = tid & 63;
  const int wave = tid >> 6;
  const int wm = wave >> 1, wn = wave & 1;
  const int l15 = lane & 15, quad = lane >> 4;

  if (z < 2) {
    _Float16* C = (z == 0) ? Q : Kb;
#pragma unroll
    for (int tm = 0; tm < 4; ++tm)
#pragma unroll
      for (int tn = 0; tn < 4; ++tn) {
        const int row = m0 + wm*64 + tm*16 + quad*4;   // C/D: row(m)=quad*4+r
        const int col = n0 + wn*64 + tn*16 + l15;      //      col(n)=lane&15
#pragma unroll
        for (int r = 0; r < 4; ++r)
          C[(size_t)(row + r)*HID + col] = (_Float16)acc[tm][tn][r];
      }
  } else {
#pragma unroll
    for (int tm = 0; tm < 4; ++tm)
#pragma unroll
      for (int tn = 0; tn < 4; ++tn) {
        const int row = m0 + wm*64 + tm*16 + quad*4;   // token (m)
        const int col = n0 + wn*64 + tn*16 + l15;      // feature (n)
        f16x4 v;
#pragma unroll
        for (int r = 0; r < 4; ++r) v[r] = (_Float16)acc[tm][tn][r];
        *(f16x4*)(Vt + (size_t)col*TOK + row) = v;     // 8B packed transposed store
      }
  }
}

__global__ __launch_bounds__(256, 2)
void gemm_o_kernel(const _Float16* __restrict__ A,
                   const _Float16* __restrict__ Wo,
                   float* __restrict__ C) {               // fp32 output
  __shared__ __align__(16) _Float16 sA[128*32];
  __shared__ __align__(16) _Float16 sB[128*32];
  const int m0 = blockIdx.y * 128;
  const int n0 = blockIdx.x * 128;
  f32x4 acc[4][4] = {};
  gemm_mainloop(A, Wo, sA, sB, acc, m0, n0);

  const int tid  = threadIdx.x;
  const int lane = tid & 63;
  const int wave = tid >> 6;
  const int wm = wave >> 1, wn = wave & 1;
  const int l15 = lane & 15, quad = lane >> 4;
#pragma unroll
  for (int tm = 0; tm < 4; ++tm)
#pragma unroll
    for (int tn = 0; tn < 4; ++tn) {
      const int row = m0 + wm*64 + tm*16 + quad*4;
      const int col = n0 + wn*64 + tn*16 + l15;
#pragma unroll
      for (int r = 0; r < 4; ++r)
        C[(size_t)(row + r)*HID + col] = acc[tm][tn][r];
    }
}

// ---------- Flash sliding-window attention ----------
// Block = 64 queries (4 waves x 16), grid (SEQ/64, NH, NB).
// O = P*V orientation: D query index = quad*4+r -> alpha/l apply register-direct.
__global__ __launch_bounds__(256, 2)
void attn_kernel(const _Float16* __restrict__ Q, const _Float16* __restrict__ Kb,
                 const _Float16* __restrict__ Vt, const int* __restrict__ AM,
                 _Float16* __restrict__ O) {
  __shared__ __align__(16) _Float16 sP[4*16*64];  // 2KB per wave: P[query][key]

  const int qt = blockIdx.x, h = blockIdx.y, b = blockIdx.z;
  const int tid  = threadIdx.x;
  const int lane = tid & 63, wave = tid >> 6;
  const int l15 = lane & 15, quad = lane >> 4;

  const int qrow = qt * 64 + wave * 16;

  // Q A-fragment: A[m=lane&15][k=quad*8+j], d=64 split in two 32-chunks
  const size_t qbase = (size_t)(b*SEQ + qrow + l15)*HID + h*HD + quad*8;
  const f16x8 qf0 = *(const f16x8*)(Q + qbase);
  const f16x8 qf1 = *(const f16x8*)(Q + qbase + 32);

  f32x4 o[4] = {};                 // O: 4 d-tiles; row(m)=query=quad*4+r, col(n)=dfeat=l15
  float m_run[4], l_run[4];
#pragma unroll
  for (int r = 0; r < 4; ++r) { m_run[r] = -1e30f; l_run[r] = 0.0f; }

  _Float16* myP = sP + wave*(16*64);
  const int i0 = qrow + quad*4;    // + r = query index within sequence

  int kt_lo = qt - 8; if (kt_lo < 0) kt_lo = 0;   // window 512 => at most 9 key tiles

  for (int kt = kt_lo; kt <= qt; ++kt) {
    const int j0 = kt * 64;
    // S = Q K^T: D[m=query=quad*4+r][n=key=l15], 4 key-subtiles x 2 k-chunks
    f32x4 sc[4] = {};
#pragma unroll
    for (int t = 0; t < 4; ++t) {
      const size_t kb = (size_t)(b*SEQ + j0 + t*16 + l15)*HID + h*HD + quad*8;
      f16x8 kf0 = *(const f16x8*)(Kb + kb);
      f16x8 kf1 = *(const f16x8*)(Kb + kb + 32);
      sc[t] = __builtin_amdgcn_mfma_f32_16x16x32_f16(qf0, kf0, sc[t], 0, 0, 0);
      sc[t] = __builtin_amdgcn_mfma_f32_16x16x32_f16(qf1, kf1, sc[t], 0, 0, 0);
    }
    // scale + causal/window/pad mask; clamp keeps everything finite
    float rmax[4] = {-1e30f, -1e30f, -1e30f, -1e30f};
#pragma unroll
    for (int t = 0; t < 4; ++t) {
      const int j = j0 + t*16 + l15;
      const bool mk = AM[b*SEQ + j] != 0;
#pragma unroll
      for (int r = 0; r < 4; ++r) {
        const int i = i0 + r;
        const bool valid = mk && (j <= i) && (j >= i - (WIN - 1));
        float s = valid ? fminf(fmaxf(sc[t][r] * 0.125f, -1e30f), 1e30f) : -1e30f;
        sc[t][r] = s;
        rmax[r] = fmaxf(rmax[r], s);
      }
    }
    // online softmax: 16-lane reduce over key lanes within each quad group
    float alpha[4];
#pragma unroll
    for (int r = 0; r < 4; ++r) {
      float v = rmax[r];
      v = fmaxf(v, __shfl_xor(v, 1, 64));
      v = fmaxf(v, __shfl_xor(v, 2, 64));
      v = fmaxf(v, __shfl_xor(v, 4, 64));
      v = fmaxf(v, __shfl_xor(v, 8, 64));
      const float mnew = fmaxf(m_run[r], v);
      alpha[r] = __expf(m_run[r] - mnew);
      m_run[r] = mnew;
      float s0 = 0.0f;
#pragma unroll
      for (int t = 0; t < 4; ++t) {
        const float p = __expf(sc[t][r] - mnew);
        sc[t][r] = p;
        s0 += p;
      }
      s0 += __shfl_xor(s0, 1, 64);
      s0 += __shfl_xor(s0, 2, 64);
      s0 += __shfl_xor(s0, 4, 64);
      s0 += __shfl_xor(s0, 8, 64);
      l_run[r] = l_run[r]*alpha[r] + s0;
    }
    // P: C-layout -> LDS [query][key] (uniform trip count -> barriers legal)
    __syncthreads();               // WAR: previous iter's P reads complete
#pragma unroll
    for (int t = 0; t < 4; ++t)
#pragma unroll
      for (int r = 0; r < 4; ++r)
        myP[(quad*4 + r)*64 + t*16 + l15] = (_Float16)sc[t][r];
    __syncthreads();               // P visible

    // rescale O by alpha (register-direct: o row = query = quad*4+r)
#pragma unroll
    for (int dt = 0; dt < 4; ++dt)
#pragma unroll
      for (int r = 0; r < 4; ++r) o[dt][r] *= alpha[r];

    // O += P V: A = P[m=query=l15][k=key=quad*8+j], B = Vt[n=dfeat=l15][k=key]
    const f16x8 pf0 = *(const f16x8*)(myP + l15*64 + quad*8);
    const f16x8 pf1 = *(const f16x8*)(myP + l15*64 + 32 + quad*8);
#pragma unroll
    for (int dt = 0; dt < 4; ++dt) {
      const size_t vb = (size_t)(h*HD + dt*16 + l15)*TOK + b*SEQ + j0 + quad*8;
      f16x8 vf0 = *(const f16x8*)(Vt + vb);
      f16x8 vf1 = *(const f16x8*)(Vt + vb + 32);
      o[dt] = __builtin_amdgcn_mfma_f32_16x16x32_f16(pf0, vf0, o[dt], 0, 0, 0);
      o[dt] = __builtin_amdgcn_mfma_f32_16x16x32_f16(pf1, vf1, o[dt], 0, 0, 0);
    }
  }
  // epilogue: divide by l (register-direct), store O[query][feat] f16
  float inv[4];
#pragma unroll
  for (int r = 0; r < 4; ++r) inv[r] = 1.0f / l_run[r];   // l > 0 always
#pragma unroll
  for (int dt = 0; dt < 4; ++dt)
#pragma unroll
    for (int r = 0; r < 4; ++r) {
      const size_t ob = (size_t)(b*SEQ + qrow + quad*4 + r)*HID + h*HD + dt*16 + l15;
      O[ob] = (_Float16)(o[dt][r] * inv[r]);
    }
}

extern "C" void kernel_launch(void* const* d_in, const int* in_sizes, int n_in,
                              void* d_out, int out_size, void* d_ws, size_t ws_size,
                              hipStream_t stream) {
  const float* X  = (const float*)d_in[0];
  const int*   AM = (const int*)d_in[1];
  const float* Wq = (const float*)d_in[2];
  const float* Wk = (const float*)d_in[3];
  const float* Wv = (const float*)d_in[4];
  const float* Wo = (const float*)d_in[5];
  float* out = (float*)d_out;

  // ws layout (f16): Xh 8M | Wh 4M | Q 8M | K 8M | Vt 8M | AO 8M  = 88 MB
  _Float16* Xh = (_Float16*)d_ws;
  _Float16* Wh = Xh + (size_t)TOK*HID;
  _Float16* Qb = Wh + (size_t)4*HID*HID;
  _Float16* Kb = Qb + (size_t)TOK*HID;
  _Float16* Vt = Kb + (size_t)TOK*HID;
  _Float16* AO = Vt + (size_t)TOK*HID;

  dim3 blk(256);
  convertX_kernel<<<dim3((TOK*HID)/(256*8)), blk, 0, stream>>>(X, Xh);
  convertW_kernel<<<dim3((HID*HID)/(256*8), 1, 4), blk, 0, stream>>>(Wq, Wk, Wv, Wo, Wh);
  gemm_qkv_kernel<<<dim3(HID/128, TOK/128, 3), blk, 0, stream>>>(Xh, Wh, Qb, Kb, Vt);
  attn_kernel<<<dim3(SEQ/64, NH, NB), blk, 0, stream>>>(Qb, Kb, Vt, AM, AO);
  gemm_o_kernel<<<dim3(HID/128, TOK/128, 1), blk, 0, stream>>>(AO, Wh + (size_t)3*HID*HID, out);
}

// Round 4
// 248.321 us; speedup vs baseline: 1.4412x; 1.4412x over previous
//
#include <hip/hip_runtime.h>
#include <cstdint>
#include <cstddef>

#define HID 1024
#define SEQ 4096
#define NB  2
#define NH  16
#define HD  64
#define WIN 512
#define TOK (NB*SEQ)   // 8192 tokens

typedef _Float16 f16x8 __attribute__((ext_vector_type(8)));
typedef _Float16 f16x4 __attribute__((ext_vector_type(4)));
typedef float    f32x4 __attribute__((ext_vector_type(4)));

// ---------- fp32 -> fp16 conversion ----------
__global__ __launch_bounds__(256)
void convertX_kernel(const float* __restrict__ src, _Float16* __restrict__ dst) {
  const int i = (blockIdx.x * 256 + threadIdx.x) * 8;
  f32x4 a = *(const f32x4*)(src + i);
  f32x4 b = *(const f32x4*)(src + i + 4);
  f16x8 o;
#pragma unroll
  for (int r = 0; r < 4; ++r) { o[r] = (_Float16)a[r]; o[r+4] = (_Float16)b[r]; }
  *(f16x8*)(dst + i) = o;
}

__global__ __launch_bounds__(256)
void convertW_kernel(const float* __restrict__ w0, const float* __restrict__ w1,
                     const float* __restrict__ w2, const float* __restrict__ w3,
                     _Float16* __restrict__ dst) {
  const int z = blockIdx.z;
  const float* s = (z == 0) ? w0 : (z == 1) ? w1 : (z == 2) ? w2 : w3;
  _Float16* d = dst + (size_t)z * HID * HID;
  const int i = (blockIdx.x * 256 + threadIdx.x) * 8;
  f32x4 a = *(const f32x4*)(s + i);
  f32x4 b = *(const f32x4*)(s + i + 4);
  f16x8 o;
#pragma unroll
  for (int r = 0; r < 4; ++r) { o[r] = (_Float16)a[r]; o[r+4] = (_Float16)b[r]; }
  *(f16x8*)(d + i) = o;
}

// async global->LDS, 16B per lane (m97-verified pattern).
__device__ __forceinline__ void gload16(const void* g, void* lds) {
  __builtin_amdgcn_global_load_lds(
      (__attribute__((address_space(1))) void*)(void*)g,
      (__attribute__((address_space(3))) void*)lds, 16, 0, 0);
}

// ---------- C = A @ W^T main loop (f16 in, f32 acc), global_load_lds staging ----------
__device__ __forceinline__ void gemm_mainloop(
    const _Float16* __restrict__ A, const _Float16* __restrict__ W,
    _Float16* sA, _Float16* sB, f32x4 (&acc)[4][4], int m0, int n0) {
  const int tid  = threadIdx.x;
  const int lane = tid & 63;
  const int wave = tid >> 6;
  const int wm = wave >> 1, wn = wave & 1;
  const int l15 = lane & 15, quad = lane >> 4;

  // staging: 128x32 f16 tile = 8KB; thread copies 16B at byte o0 and o0+4096.
  const int o0 = tid * 16;
  const int o1 = o0 + 4096;
  const _Float16* a0 = A + (size_t)(m0 + (o0 >> 6)) * HID + ((o0 & 63) >> 1);
  const _Float16* a1 = A + (size_t)(m0 + (o1 >> 6)) * HID + ((o1 & 63) >> 1);
  const _Float16* w0 = W + (size_t)(n0 + (o0 >> 6)) * HID + ((o0 & 63) >> 1);
  const _Float16* w1 = W + (size_t)(n0 + (o1 >> 6)) * HID + ((o1 & 63) >> 1);
  _Float16* la0 = sA + (o0 >> 1);
  _Float16* la1 = sA + (o1 >> 1);
  _Float16* lb0 = sB + (o0 >> 1);
  _Float16* lb1 = sB + (o1 >> 1);

  const int aoff = (wm*64 + l15)*32 + quad*8;
  const int boff = (wn*64 + l15)*32 + quad*8;

  for (int k0 = 0; k0 < HID; k0 += 32) {
    __syncthreads();                 // WAR: prior iter's LDS reads done
    gload16(a0 + k0, la0);
    gload16(a1 + k0, la1);
    gload16(w0 + k0, lb0);
    gload16(w1 + k0, lb1);
    __syncthreads();                 // staging complete
    f16x8 af[4], wf[4];
#pragma unroll
    for (int t = 0; t < 4; ++t) {
      af[t] = *(const f16x8*)(sA + aoff + t*512);
      wf[t] = *(const f16x8*)(sB + boff + t*512);
    }
#pragma unroll
    for (int i = 0; i < 4; ++i)
#pragma unroll
      for (int j = 0; j < 4; ++j)
        acc[i][j] = __builtin_amdgcn_mfma_f32_16x16x32_f16(af[i], wf[j], acc[i][j], 0, 0, 0);
  }
}

// z=0: Q (scaled by 1/8), z=1: K; z=2: V transposed Vt[feat][token]
__global__ __launch_bounds__(256, 2)
void gemm_qkv_kernel(const _Float16* __restrict__ X,
                     const _Float16* __restrict__ Wh,
                     _Float16* __restrict__ Q,
                     _Float16* __restrict__ Kb,
                     _Float16* __restrict__ Vt) {
  __shared__ __align__(16) _Float16 sA[128*32];
  __shared__ __align__(16) _Float16 sB[128*32];
  const int z = blockIdx.z;
  const _Float16* W = Wh + (size_t)z * HID * HID;
  const int m0 = blockIdx.y * 128;
  const int n0 = blockIdx.x * 128;
  f32x4 acc[4][4] = {};
  gemm_mainloop(X, W, sA, sB, acc, m0, n0);

  const int tid  = threadIdx.x;
  const int lane = tid & 63;
  const int wave = tid >> 6;
  const int wm = wave >> 1, wn = wave & 1;
  const int l15 = lane & 15, quad = lane >> 4;

  if (z < 2) {
    _Float16* C = (z == 0) ? Q : Kb;
    const float scl = (z == 0) ? 0.125f : 1.0f;   // fold softmax scale into Q
#pragma unroll
    for (int tm = 0; tm < 4; ++tm)
#pragma unroll
      for (int tn = 0; tn < 4; ++tn) {
        const int row = m0 + wm*64 + tm*16 + quad*4;
        const int col = n0 + wn*64 + tn*16 + l15;
#pragma unroll
        for (int r = 0; r < 4; ++r)
          C[(size_t)(row + r)*HID + col] = (_Float16)(acc[tm][tn][r] * scl);
      }
  } else {
#pragma unroll
    for (int tm = 0; tm < 4; ++tm)
#pragma unroll
      for (int tn = 0; tn < 4; ++tn) {
        const int row = m0 + wm*64 + tm*16 + quad*4;   // token
        const int col = n0 + wn*64 + tn*16 + l15;      // feature
        f16x4 v;
#pragma unroll
        for (int r = 0; r < 4; ++r) v[r] = (_Float16)acc[tm][tn][r];
        *(f16x4*)(Vt + (size_t)col*TOK + row) = v;
      }
  }
}

__global__ __launch_bounds__(256, 2)
void gemm_o_kernel(const _Float16* __restrict__ A,
                   const _Float16* __restrict__ Wo,
                   float* __restrict__ C) {
  __shared__ __align__(16) _Float16 sA[128*32];
  __shared__ __align__(16) _Float16 sB[128*32];
  const int m0 = blockIdx.y * 128;
  const int n0 = blockIdx.x * 128;
  f32x4 acc[4][4] = {};
  gemm_mainloop(A, Wo, sA, sB, acc, m0, n0);

  const int tid  = threadIdx.x;
  const int lane = tid & 63;
  const int wave = tid >> 6;
  const int wm = wave >> 1, wn = wave & 1;
  const int l15 = lane & 15, quad = lane >> 4;
#pragma unroll
  for (int tm = 0; tm < 4; ++tm)
#pragma unroll
    for (int tn = 0; tn < 4; ++tn) {
      const int row = m0 + wm*64 + tm*16 + quad*4;
      const int col = n0 + wn*64 + tn*16 + l15;
#pragma unroll
      for (int r = 0; r < 4; ++r)
        C[(size_t)(row + r)*HID + col] = acc[tm][tn][r];
    }
}

// ---------- Flash sliding-window attention, S^T orientation ----------
// Block = 128 queries (4 waves x 32), grid (SEQ/128, NH, NB).
// K/V tiles (64 keys) staged in LDS, shared by all 4 waves, register-prefetch
// double buffered. XOR-swizzled LDS (2-way conflicts). Softmax stats per-l15
// lane (query) -> 4 shuffles/iter, alpha/l register-direct on O^T accumulator.
__global__ __launch_bounds__(256, 2)
void attn_kernel(const _Float16* __restrict__ Q, const _Float16* __restrict__ Kb,
                 const _Float16* __restrict__ Vt, const int* __restrict__ AM,
                 _Float16* __restrict__ O) {
  __shared__ __align__(16) _Float16 sK[64*64];     // 8KB  [key][d]     swizzled
  __shared__ __align__(16) _Float16 sV[64*64];     // 8KB  [dfeat][key] swizzled
  __shared__ __align__(16) _Float16 sP[4*32*64];   // 16KB [query][key] swizzled, per-wave
  __shared__ int sOK;

  const int qt = blockIdx.x, h = blockIdx.y, b = blockIdx.z;
  const int tid  = threadIdx.x;
  const int lane = tid & 63, wave = tid >> 6;
  const int l15 = lane & 15, quad = lane >> 4;

  const int q0 = qt * 128;
  const int qw = q0 + wave * 32;        // wave's first query

  // swizzle constants (row&7 == l15&7 for all fragment rows used)
  const int swz = l15 & 7;
  const int cA8 = ((quad ^ swz) << 3);          // f16 offset, k-chunk 0..31
  const int cB8 = (((quad + 4) ^ swz) << 3);    // f16 offset, k-chunk 32..63

  // Q fragments: B[n=query=l15][k=d=quad*8+j]; Q pre-scaled by 1/8.
  f16x8 qf[2][2];
#pragma unroll
  for (int ns = 0; ns < 2; ++ns) {
    const size_t qb = (size_t)(b*SEQ + qw + ns*16 + l15)*HID + h*HD + quad*8;
    qf[ns][0] = *(const f16x8*)(Q + qb);
    qf[ns][1] = *(const f16x8*)(Q + qb + 32);
  }

  const int kt_hi = 2*qt + 1;
  int kt_lo = 2*qt - 8; if (kt_lo < 0) kt_lo = 0;

  // attention_mask all-ones precheck (block-uniform fast path)
  if (tid == 0) sOK = 1;
  __syncthreads();
  {
    int ok = 1;
    const int jbeg = kt_lo*64, jend = (kt_hi + 1)*64;
    for (int j = jbeg + tid; j < jend; j += 256) ok &= (AM[b*SEQ + j] != 0);
    if (!ok) sOK = 0;
  }
  __syncthreads();
  const bool allok = (sOK != 0);

  // prefetch addressing: thread covers rows prow, prow+32 with swizzled chunk pc
  const int prow = tid >> 3;          // 0..31
  const int pc   = tid & 7;
  const int pco  = ((pc ^ (prow & 7)) << 3);     // same for prow+32 ((r+32)&7==r&7)
  f16x8 pk0, pk1, pv0, pv1;
  {
    const int j0 = kt_lo * 64;
    const _Float16* kp = Kb + (size_t)(b*SEQ + j0 + prow)*HID + h*HD + pco;
    pk0 = *(const f16x8*)kp;
    pk1 = *(const f16x8*)(kp + (size_t)32*HID);
    const _Float16* vp = Vt + (size_t)(h*HD + prow)*TOK + b*SEQ + j0 + pco;
    pv0 = *(const f16x8*)vp;
    pv1 = *(const f16x8*)(vp + (size_t)32*TOK);
  }

  float m_run[2] = {-1e20f, -1e20f}, l_run[2] = {0.0f, 0.0f};
  f32x4 o[4][2] = {};
  _Float16* myP = sP + wave * (32*64);

  for (int kt = kt_lo; kt <= kt_hi; ++kt) {
    const int j0 = kt * 64;
    __syncthreads();                  // prior iter's LDS reads done
    *(f16x8*)(sK + tid*8)        = pk0;
    *(f16x8*)(sK + tid*8 + 2048) = pk1;
    *(f16x8*)(sV + tid*8)        = pv0;
    *(f16x8*)(sV + tid*8 + 2048) = pv1;
    __syncthreads();                  // staging visible
    if (kt < kt_hi) {
      int jn = (kt + 1) * 64; if (jn > SEQ - 64) jn = SEQ - 64;
      const _Float16* kp = Kb + (size_t)(b*SEQ + jn + prow)*HID + h*HD + pco;
      pk0 = *(const f16x8*)kp;
      pk1 = *(const f16x8*)(kp + (size_t)32*HID);
      const _Float16* vp = Vt + (size_t)(h*HD + prow)*TOK + b*SEQ + jn + pco;
      pv0 = *(const f16x8*)vp;
      pv1 = *(const f16x8*)(vp + (size_t)32*TOK);
    }

    // S^T = K Q^T: sc[t][ns] D[m=key=t*16+quad*4+r][n=query=ns*16+l15]
    f32x4 sc[4][2] = {};
#pragma unroll
    for (int t = 0; t < 4; ++t) {
      const f16x8 kf0 = *(const f16x8*)(sK + (t*16 + l15)*64 + cA8);
      const f16x8 kf1 = *(const f16x8*)(sK + (t*16 + l15)*64 + cB8);
      sc[t][0] = __builtin_amdgcn_mfma_f32_16x16x32_f16(kf0, qf[0][0], sc[t][0], 0, 0, 0);
      sc[t][0] = __builtin_amdgcn_mfma_f32_16x16x32_f16(kf1, qf[0][1], sc[t][0], 0, 0, 0);
      sc[t][1] = __builtin_amdgcn_mfma_f32_16x16x32_f16(kf0, qf[1][0], sc[t][1], 0, 0, 0);
      sc[t][1] = __builtin_amdgcn_mfma_f32_16x16x32_f16(kf1, qf[1][1], sc[t][1], 0, 0, 0);
    }

    // pad mask (slow path only; never taken for all-ones mask)
    if (!allok) {
#pragma unroll
      for (int t = 0; t < 4; ++t)
#pragma unroll
        for (int r = 0; r < 4; ++r) {
          const float ad = (AM[b*SEQ + j0 + t*16 + quad*4 + r] == 0) ? -2e30f : 0.0f;
          sc[t][0][r] += ad;
          sc[t][1][r] += ad;
        }
    }

    // window mask + online softmax per ns (stats per query = per l15 lane)
#pragma unroll
    for (int ns = 0; ns < 2; ++ns) {
      const int i = qw + ns*16 + l15;
      float mx = -1e30f;
#pragma unroll
      for (int t = 0; t < 4; ++t)
#pragma unroll
        for (int r = 0; r < 4; ++r) {
          const int j = j0 + t*16 + quad*4 + r;
          const bool valid = (unsigned)(i - j) < WIN;   // j<=i && i-j<512
          const float s = valid ? sc[t][ns][r] : -1e30f;
          sc[t][ns][r] = s;
          mx = fmaxf(mx, s);
        }
      mx = fmaxf(mx, __shfl_xor(mx, 16, 64));
      mx = fmaxf(mx, __shfl_xor(mx, 32, 64));
      const float mnew = fmaxf(m_run[ns], mx);          // >= -1e20: all-masked safe
      const float alpha = __expf(m_run[ns] - mnew);
      m_run[ns] = mnew;
      float sum = 0.0f;
#pragma unroll
      for (int t = 0; t < 4; ++t) {
        f16x4 pv;
#pragma unroll
        for (int r = 0; r < 4; ++r) {
          const float p = __expf(sc[t][ns][r] - mnew);
          sum += p;
          pv[r] = (_Float16)p;
        }
        // P[query][key] swizzled: row=ns*16+l15, keys t*16+quad*4..+3
        const int paddr = (ns*16 + l15)*64 + (((2*t + (quad >> 1)) ^ swz) << 3) + (quad & 1)*4;
        *(f16x4*)(myP + paddr) = pv;
      }
      sum += __shfl_xor(sum, 16, 64);
      sum += __shfl_xor(sum, 32, 64);
      l_run[ns] = l_run[ns]*alpha + sum;
#pragma unroll
      for (int dt = 0; dt < 4; ++dt)
#pragma unroll
        for (int r = 0; r < 4; ++r) o[dt][ns][r] *= alpha;
    }

    // O^T += V^T P^T (wave-private P; in-wave DS ordering, no barrier needed)
    const f16x8 pf00 = *(const f16x8*)(myP + l15*64 + cA8);
    const f16x8 pf01 = *(const f16x8*)(myP + l15*64 + cB8);
    const f16x8 pf10 = *(const f16x8*)(myP + (16 + l15)*64 + cA8);
    const f16x8 pf11 = *(const f16x8*)(myP + (16 + l15)*64 + cB8);
#pragma unroll
    for (int dt = 0; dt < 4; ++dt) {
      const f16x8 vf0 = *(const f16x8*)(sV + (dt*16 + l15)*64 + cA8);
      const f16x8 vf1 = *(const f16x8*)(sV + (dt*16 + l15)*64 + cB8);
      o[dt][0] = __builtin_amdgcn_mfma_f32_16x16x32_f16(vf0, pf00, o[dt][0], 0, 0, 0);
      o[dt][0] = __builtin_amdgcn_mfma_f32_16x16x32_f16(vf1, pf01, o[dt][0], 0, 0, 0);
      o[dt][1] = __builtin_amdgcn_mfma_f32_16x16x32_f16(vf0, pf10, o[dt][1], 0, 0, 0);
      o[dt][1] = __builtin_amdgcn_mfma_f32_16x16x32_f16(vf1, pf11, o[dt][1], 0, 0, 0);
    }
  }

  // epilogue: O^T[m=dfeat=dt*16+quad*4+r][n=query=ns*16+l15] -> O[query][feat]
  const float inv[2] = {1.0f / fmaxf(l_run[0], 1e-30f), 1.0f / fmaxf(l_run[1], 1e-30f)};
#pragma unroll
  for (int ns = 0; ns < 2; ++ns) {
    const size_t ob = (size_t)(b*SEQ + qw + ns*16 + l15)*HID + h*HD + quad*4;
#pragma unroll
    for (int dt = 0; dt < 4; ++dt) {
      f16x4 v;
#pragma unroll
      for (int r = 0; r < 4; ++r) v[r] = (_Float16)(o[dt][ns][r] * inv[ns]);
      *(f16x4*)(O + ob + dt*16) = v;
    }
  }
}

extern "C" void kernel_launch(void* const* d_in, const int* in_sizes, int n_in,
                              void* d_out, int out_size, void* d_ws, size_t ws_size,
                              hipStream_t stream) {
  const float* X  = (const float*)d_in[0];
  const int*   AM = (const int*)d_in[1];
  const float* Wq = (const float*)d_in[2];
  const float* Wk = (const float*)d_in[3];
  const float* Wv = (const float*)d_in[4];
  const float* Wo = (const float*)d_in[5];
  float* out = (float*)d_out;

  _Float16* Xh = (_Float16*)d_ws;
  _Float16* Wh = Xh + (size_t)TOK*HID;
  _Float16* Qb = Wh + (size_t)4*HID*HID;
  _Float16* Kb = Qb + (size_t)TOK*HID;
  _Float16* Vt = Kb + (size_t)TOK*HID;
  _Float16* AO = Vt + (size_t)TOK*HID;

  dim3 blk(256);
  convertX_kernel<<<dim3((TOK*HID)/(256*8)), blk, 0, stream>>>(X, Xh);
  convertW_kernel<<<dim3((HID*HID)/(256*8), 1, 4), blk, 0, stream>>>(Wq, Wk, Wv, Wo, Wh);
  gemm_qkv_kernel<<<dim3(HID/128, TOK/128, 3), blk, 0, stream>>>(Xh, Wh, Qb, Kb, Vt);
  attn_kernel<<<dim3(SEQ/128, NH, NB), blk, 0, stream>>>(Qb, Kb, Vt, AM, AO);
  gemm_o_kernel<<<dim3(HID/128, TOK/128, 1), blk, 0, stream>>>(AO, Wh + (size_t)3*HID*HID, out);
}

// Round 5
// 241.615 us; speedup vs baseline: 1.4812x; 1.0278x over previous
//
#include <hip/hip_runtime.h>
#include <cstdint>
#include <cstddef>

#define HID 1024
#define SEQ 4096
#define NB  2
#define NH  16
#define HD  64
#define WIN 512
#define TOK (NB*SEQ)   // 8192 tokens

typedef _Float16 f16x8 __attribute__((ext_vector_type(8)));
typedef _Float16 f16x4 __attribute__((ext_vector_type(4)));
typedef float    f32x4 __attribute__((ext_vector_type(4)));

// ---------- fp32 -> fp16 conversion ----------
__global__ __launch_bounds__(256)
void convertX_kernel(const float* __restrict__ src, _Float16* __restrict__ dst) {
  const int i = (blockIdx.x * 256 + threadIdx.x) * 8;
  f32x4 a = *(const f32x4*)(src + i);
  f32x4 b = *(const f32x4*)(src + i + 4);
  f16x8 o;
#pragma unroll
  for (int r = 0; r < 4; ++r) { o[r] = (_Float16)a[r]; o[r+4] = (_Float16)b[r]; }
  *(f16x8*)(dst + i) = o;
}

__global__ __launch_bounds__(256)
void convertW_kernel(const float* __restrict__ w0, const float* __restrict__ w1,
                     const float* __restrict__ w2, const float* __restrict__ w3,
                     _Float16* __restrict__ dst) {
  const int z = blockIdx.z;
  const float* s = (z == 0) ? w0 : (z == 1) ? w1 : (z == 2) ? w2 : w3;
  _Float16* d = dst + (size_t)z * HID * HID;
  const int i = (blockIdx.x * 256 + threadIdx.x) * 8;
  f32x4 a = *(const f32x4*)(s + i);
  f32x4 b = *(const f32x4*)(s + i + 4);
  f16x8 o;
#pragma unroll
  for (int r = 0; r < 4; ++r) { o[r] = (_Float16)a[r]; o[r+4] = (_Float16)b[r]; }
  *(f16x8*)(d + i) = o;
}

// async global->LDS, 16B per lane (m97-verified; LDS dest = uniform base + lane*16)
__device__ __forceinline__ void gload16(const void* g, void* lds) {
  __builtin_amdgcn_global_load_lds(
      (__attribute__((address_space(1))) void*)(void*)g,
      (__attribute__((address_space(3))) void*)lds, 16, 0, 0);
}

// ---------- C = A @ W^T main loop, BK=64 as two m97-pattern 8KB sub-tiles ----------
// A:[M,1024] f16 row-major, W:[N,1024] f16 row-major. 128x128 tile,
// 4 waves x (64x64 via 4x4 grid of 16x16x32 MFMAs). One barrier pair / 32 MFMA.
__device__ __forceinline__ void gemm_mainloop(
    const _Float16* __restrict__ A, const _Float16* __restrict__ W,
    _Float16* sA, _Float16* sB, f32x4 (&acc)[4][4], int m0, int n0) {
  const int tid  = threadIdx.x;
  const int lane = tid & 63;
  const int wave = tid >> 6;
  const int wm = wave >> 1, wn = wave & 1;
  const int l15 = lane & 15, quad = lane >> 4;

  // staging: each 8KB sub-tile is 128 rows x 32 cols f16; thread copies 16B at
  // byte o0 and o0+4096 within a sub-tile. Sub-tile 1 (k+32) lives at +4096 f16.
  const int o0 = tid * 16;
  const int o1 = o0 + 4096;
  const _Float16* a0 = A + (size_t)(m0 + (o0 >> 6)) * HID + ((o0 & 63) >> 1);
  const _Float16* a1 = A + (size_t)(m0 + (o1 >> 6)) * HID + ((o1 & 63) >> 1);
  const _Float16* w0 = W + (size_t)(n0 + (o0 >> 6)) * HID + ((o0 & 63) >> 1);
  const _Float16* w1 = W + (size_t)(n0 + (o1 >> 6)) * HID + ((o1 & 63) >> 1);
  _Float16* la0 = sA + (o0 >> 1);
  _Float16* la1 = sA + (o1 >> 1);
  _Float16* lb0 = sB + (o0 >> 1);
  _Float16* lb1 = sB + (o1 >> 1);

  const int aoff = (wm*64 + l15)*32 + quad*8;
  const int boff = (wn*64 + l15)*32 + quad*8;

  for (int k0 = 0; k0 < HID; k0 += 64) {
    __syncthreads();                 // WAR: prior iter's LDS reads done
    gload16(a0 + k0,      la0);
    gload16(a1 + k0,      la1);
    gload16(a0 + k0 + 32, la0 + 4096);
    gload16(a1 + k0 + 32, la1 + 4096);
    gload16(w0 + k0,      lb0);
    gload16(w1 + k0,      lb1);
    gload16(w0 + k0 + 32, lb0 + 4096);
    gload16(w1 + k0 + 32, lb1 + 4096);
    __syncthreads();                 // staging complete
#pragma unroll
    for (int s = 0; s < 2; ++s) {
      const int sb = s * 4096;
      f16x8 af[4], wf[4];
#pragma unroll
      for (int t = 0; t < 4; ++t) {
        af[t] = *(const f16x8*)(sA + sb + aoff + t*512);
        wf[t] = *(const f16x8*)(sB + sb + boff + t*512);
      }
#pragma unroll
      for (int i = 0; i < 4; ++i)
#pragma unroll
        for (int j = 0; j < 4; ++j)
          acc[i][j] = __builtin_amdgcn_mfma_f32_16x16x32_f16(af[i], wf[j], acc[i][j], 0, 0, 0);
    }
  }
}

// QKV, 1-D grid 1536 blocks, XCD-aware decode (XCD = blockIdx%8):
// each XCD gets runs of 64 consecutive blocks with one (n,z) W-slab (L2-resident).
__global__ __launch_bounds__(256, 2)
void gemm_qkv_kernel(const _Float16* __restrict__ X,
                     const _Float16* __restrict__ Wh,
                     _Float16* __restrict__ Q,
                     _Float16* __restrict__ Kb,
                     _Float16* __restrict__ Vt) {
  __shared__ __align__(16) _Float16 sA[128*64];
  __shared__ __align__(16) _Float16 sB[128*64];
  const int i = blockIdx.x;
  const int g = i & 7;              // XCD
  const int j = i >> 3;             // 0..191
  const int c = g*3 + (j >> 6);     // 0..23 -> (n,z)
  const int z = c % 3;
  const int n0 = (c / 3) * 128;
  const int m0 = (j & 63) * 128;
  const _Float16* W = Wh + (size_t)z * HID * HID;
  f32x4 acc[4][4] = {};
  gemm_mainloop(X, W, sA, sB, acc, m0, n0);

  const int tid  = threadIdx.x;
  const int lane = tid & 63;
  const int wave = tid >> 6;
  const int wm = wave >> 1, wn = wave & 1;
  const int l15 = lane & 15, quad = lane >> 4;

  if (z < 2) {
    _Float16* C = (z == 0) ? Q : Kb;
    const float scl = (z == 0) ? 0.125f : 1.0f;   // fold softmax scale into Q
#pragma unroll
    for (int tm = 0; tm < 4; ++tm)
#pragma unroll
      for (int tn = 0; tn < 4; ++tn) {
        const int row = m0 + wm*64 + tm*16 + quad*4;
        const int col = n0 + wn*64 + tn*16 + l15;
#pragma unroll
        for (int r = 0; r < 4; ++r)
          C[(size_t)(row + r)*HID + col] = (_Float16)(acc[tm][tn][r] * scl);
      }
  } else {
#pragma unroll
    for (int tm = 0; tm < 4; ++tm)
#pragma unroll
      for (int tn = 0; tn < 4; ++tn) {
        const int row = m0 + wm*64 + tm*16 + quad*4;   // token
        const int col = n0 + wn*64 + tn*16 + l15;      // feature
        f16x4 v;
#pragma unroll
        for (int r = 0; r < 4; ++r) v[r] = (_Float16)acc[tm][tn][r];
        *(f16x4*)(Vt + (size_t)col*TOK + row) = v;
      }
  }
}

// O-proj, 1-D grid 512 blocks: XCD g owns n-slab g (W L2-resident), m streams.
__global__ __launch_bounds__(256, 2)
void gemm_o_kernel(const _Float16* __restrict__ A,
                   const _Float16* __restrict__ Wo,
                   float* __restrict__ C) {
  __shared__ __align__(16) _Float16 sA[128*64];
  __shared__ __align__(16) _Float16 sB[128*64];
  const int i = blockIdx.x;
  const int n0 = (i & 7) * 128;
  const int m0 = (i >> 3) * 128;
  f32x4 acc[4][4] = {};
  gemm_mainloop(A, Wo, sA, sB, acc, m0, n0);

  const int tid  = threadIdx.x;
  const int lane = tid & 63;
  const int wave = tid >> 6;
  const int wm = wave >> 1, wn = wave & 1;
  const int l15 = lane & 15, quad = lane >> 4;
#pragma unroll
  for (int tm = 0; tm < 4; ++tm)
#pragma unroll
    for (int tn = 0; tn < 4; ++tn) {
      const int row = m0 + wm*64 + tm*16 + quad*4;
      const int col = n0 + wn*64 + tn*16 + l15;
#pragma unroll
      for (int r = 0; r < 4; ++r)
        C[(size_t)(row + r)*HID + col] = acc[tm][tn][r];
    }
}

// ---------- Flash sliding-window attention, S^T orientation ----------
// 1-D grid 1024 blocks; XCD-aware decode clusters each (b,h)'s 2MB K/V on one XCD.
__global__ __launch_bounds__(256, 2)
void attn_kernel(const _Float16* __restrict__ Q, const _Float16* __restrict__ Kb,
                 const _Float16* __restrict__ Vt, const int* __restrict__ AM,
                 _Float16* __restrict__ O) {
  __shared__ __align__(16) _Float16 sK[64*64];     // 8KB  [key][d]     swizzled
  __shared__ __align__(16) _Float16 sV[64*64];     // 8KB  [dfeat][key] swizzled
  __shared__ __align__(16) _Float16 sP[4*32*64];   // 16KB [query][key] swizzled, per-wave
  __shared__ int sOK;

  const int bi = blockIdx.x;
  const int g  = bi & 7;                // XCD
  const int jj = bi >> 3;               // 0..127
  const int combo = g*4 + (jj >> 5);    // 0..31 -> (b,h)
  const int h = combo & 15, b = combo >> 4;
  const int qt = jj & 31;

  const int tid  = threadIdx.x;
  const int lane = tid & 63, wave = tid >> 6;
  const int l15 = lane & 15, quad = lane >> 4;

  const int q0 = qt * 128;
  const int qw = q0 + wave * 32;        // wave's first query

  const int swz = l15 & 7;
  const int cA8 = ((quad ^ swz) << 3);
  const int cB8 = (((quad + 4) ^ swz) << 3);

  // Q fragments: B[n=query=l15][k=d=quad*8+j]; Q pre-scaled by 1/8.
  f16x8 qf[2][2];
#pragma unroll
  for (int ns = 0; ns < 2; ++ns) {
    const size_t qb = (size_t)(b*SEQ + qw + ns*16 + l15)*HID + h*HD + quad*8;
    qf[ns][0] = *(const f16x8*)(Q + qb);
    qf[ns][1] = *(const f16x8*)(Q + qb + 32);
  }

  const int kt_hi = 2*qt + 1;
  int kt_lo = 2*qt - 8; if (kt_lo < 0) kt_lo = 0;

  // attention_mask all-ones precheck (block-uniform fast path)
  if (tid == 0) sOK = 1;
  __syncthreads();
  {
    int ok = 1;
    const int jbeg = kt_lo*64, jend = (kt_hi + 1)*64;
    for (int j = jbeg + tid; j < jend; j += 256) ok &= (AM[b*SEQ + j] != 0);
    if (!ok) sOK = 0;
  }
  __syncthreads();
  const bool allok = (sOK != 0);

  // prefetch addressing: thread covers rows prow, prow+32 with swizzled chunk pc
  const int prow = tid >> 3;
  const int pc   = tid & 7;
  const int pco  = ((pc ^ (prow & 7)) << 3);
  f16x8 pk0, pk1, pv0, pv1;
  {
    const int j0 = kt_lo * 64;
    const _Float16* kp = Kb + (size_t)(b*SEQ + j0 + prow)*HID + h*HD + pco;
    pk0 = *(const f16x8*)kp;
    pk1 = *(const f16x8*)(kp + (size_t)32*HID);
    const _Float16* vp = Vt + (size_t)(h*HD + prow)*TOK + b*SEQ + j0 + pco;
    pv0 = *(const f16x8*)vp;
    pv1 = *(const f16x8*)(vp + (size_t)32*TOK);
  }

  float m_run[2] = {-1e20f, -1e20f}, l_run[2] = {0.0f, 0.0f};
  f32x4 o[4][2] = {};
  _Float16* myP = sP + wave * (32*64);

  for (int kt = kt_lo; kt <= kt_hi; ++kt) {
    const int j0 = kt * 64;
    __syncthreads();
    *(f16x8*)(sK + tid*8)        = pk0;
    *(f16x8*)(sK + tid*8 + 2048) = pk1;
    *(f16x8*)(sV + tid*8)        = pv0;
    *(f16x8*)(sV + tid*8 + 2048) = pv1;
    __syncthreads();
    if (kt < kt_hi) {
      int jn = (kt + 1) * 64; if (jn > SEQ - 64) jn = SEQ - 64;
      const _Float16* kp = Kb + (size_t)(b*SEQ + jn + prow)*HID + h*HD + pco;
      pk0 = *(const f16x8*)kp;
      pk1 = *(const f16x8*)(kp + (size_t)32*HID);
      const _Float16* vp = Vt + (size_t)(h*HD + prow)*TOK + b*SEQ + jn + pco;
      pv0 = *(const f16x8*)vp;
      pv1 = *(const f16x8*)(vp + (size_t)32*TOK);
    }

    // S^T = K Q^T: sc[t][ns] D[m=key=t*16+quad*4+r][n=query=ns*16+l15]
    f32x4 sc[4][2] = {};
#pragma unroll
    for (int t = 0; t < 4; ++t) {
      const f16x8 kf0 = *(const f16x8*)(sK + (t*16 + l15)*64 + cA8);
      const f16x8 kf1 = *(const f16x8*)(sK + (t*16 + l15)*64 + cB8);
      sc[t][0] = __builtin_amdgcn_mfma_f32_16x16x32_f16(kf0, qf[0][0], sc[t][0], 0, 0, 0);
      sc[t][0] = __builtin_amdgcn_mfma_f32_16x16x32_f16(kf1, qf[0][1], sc[t][0], 0, 0, 0);
      sc[t][1] = __builtin_amdgcn_mfma_f32_16x16x32_f16(kf0, qf[1][0], sc[t][1], 0, 0, 0);
      sc[t][1] = __builtin_amdgcn_mfma_f32_16x16x32_f16(kf1, qf[1][1], sc[t][1], 0, 0, 0);
    }

    if (!allok) {
#pragma unroll
      for (int t = 0; t < 4; ++t)
#pragma unroll
        for (int r = 0; r < 4; ++r) {
          const float ad = (AM[b*SEQ + j0 + t*16 + quad*4 + r] == 0) ? -2e30f : 0.0f;
          sc[t][0][r] += ad;
          sc[t][1][r] += ad;
        }
    }

    // window mask + online softmax (stats per query = per l15 lane)
#pragma unroll
    for (int ns = 0; ns < 2; ++ns) {
      const int i = qw + ns*16 + l15;
      float mx = -1e30f;
#pragma unroll
      for (int t = 0; t < 4; ++t)
#pragma unroll
        for (int r = 0; r < 4; ++r) {
          const int j = j0 + t*16 + quad*4 + r;
          const bool valid = (unsigned)(i - j) < WIN;
          const float s = valid ? sc[t][ns][r] : -1e30f;
          sc[t][ns][r] = s;
          mx = fmaxf(mx, s);
        }
      mx = fmaxf(mx, __shfl_xor(mx, 16, 64));
      mx = fmaxf(mx, __shfl_xor(mx, 32, 64));
      const float mnew = fmaxf(m_run[ns], mx);
      const float alpha = __expf(m_run[ns] - mnew);
      m_run[ns] = mnew;
      float sum = 0.0f;
#pragma unroll
      for (int t = 0; t < 4; ++t) {
        f16x4 pv;
#pragma unroll
        for (int r = 0; r < 4; ++r) {
          const float p = __expf(sc[t][ns][r] - mnew);
          sum += p;
          pv[r] = (_Float16)p;
        }
        const int paddr = (ns*16 + l15)*64 + (((2*t + (quad >> 1)) ^ swz) << 3) + (quad & 1)*4;
        *(f16x4*)(myP + paddr) = pv;
      }
      sum += __shfl_xor(sum, 16, 64);
      sum += __shfl_xor(sum, 32, 64);
      l_run[ns] = l_run[ns]*alpha + sum;
#pragma unroll
      for (int dt = 0; dt < 4; ++dt)
#pragma unroll
        for (int r = 0; r < 4; ++r) o[dt][ns][r] *= alpha;
    }

    // O^T += V^T P^T (wave-private P; in-wave DS ordering)
    const f16x8 pf00 = *(const f16x8*)(myP + l15*64 + cA8);
    const f16x8 pf01 = *(const f16x8*)(myP + l15*64 + cB8);
    const f16x8 pf10 = *(const f16x8*)(myP + (16 + l15)*64 + cA8);
    const f16x8 pf11 = *(const f16x8*)(myP + (16 + l15)*64 + cB8);
#pragma unroll
    for (int dt = 0; dt < 4; ++dt) {
      const f16x8 vf0 = *(const f16x8*)(sV + (dt*16 + l15)*64 + cA8);
      const f16x8 vf1 = *(const f16x8*)(sV + (dt*16 + l15)*64 + cB8);
      o[dt][0] = __builtin_amdgcn_mfma_f32_16x16x32_f16(vf0, pf00, o[dt][0], 0, 0, 0);
      o[dt][0] = __builtin_amdgcn_mfma_f32_16x16x32_f16(vf1, pf01, o[dt][0], 0, 0, 0);
      o[dt][1] = __builtin_amdgcn_mfma_f32_16x16x32_f16(vf0, pf10, o[dt][1], 0, 0, 0);
      o[dt][1] = __builtin_amdgcn_mfma_f32_16x16x32_f16(vf1, pf11, o[dt][1], 0, 0, 0);
    }
  }

  // epilogue: O^T[m=dfeat][n=query] -> O[query][feat]
  const float inv[2] = {1.0f / fmaxf(l_run[0], 1e-30f), 1.0f / fmaxf(l_run[1], 1e-30f)};
#pragma unroll
  for (int ns = 0; ns < 2; ++ns) {
    const size_t ob = (size_t)(b*SEQ + qw + ns*16 + l15)*HID + h*HD + quad*4;
#pragma unroll
    for (int dt = 0; dt < 4; ++dt) {
      f16x4 v;
#pragma unroll
      for (int r = 0; r < 4; ++r) v[r] = (_Float16)(o[dt][ns][r] * inv[ns]);
      *(f16x4*)(O + ob + dt*16) = v;
    }
  }
}

extern "C" void kernel_launch(void* const* d_in, const int* in_sizes, int n_in,
                              void* d_out, int out_size, void* d_ws, size_t ws_size,
                              hipStream_t stream) {
  const float* X  = (const float*)d_in[0];
  const int*   AM = (const int*)d_in[1];
  const float* Wq = (const float*)d_in[2];
  const float* Wk = (const float*)d_in[3];
  const float* Wv = (const float*)d_in[4];
  const float* Wo = (const float*)d_in[5];
  float* out = (float*)d_out;

  _Float16* Xh = (_Float16*)d_ws;
  _Float16* Wh = Xh + (size_t)TOK*HID;
  _Float16* Qb = Wh + (size_t)4*HID*HID;
  _Float16* Kb = Qb + (size_t)TOK*HID;
  _Float16* Vt = Kb + (size_t)TOK*HID;
  _Float16* AO = Vt + (size_t)TOK*HID;

  dim3 blk(256);
  convertX_kernel<<<dim3((TOK*HID)/(256*8)), blk, 0, stream>>>(X, Xh);
  convertW_kernel<<<dim3((HID*HID)/(256*8), 1, 4), blk, 0, stream>>>(Wq, Wk, Wv, Wo, Wh);
  gemm_qkv_kernel<<<dim3(1536), blk, 0, stream>>>(Xh, Wh, Qb, Kb, Vt);
  attn_kernel<<<dim3(1024), blk, 0, stream>>>(Qb, Kb, Vt, AM, AO);
  gemm_o_kernel<<<dim3(512), blk, 0, stream>>>(AO, Wh + (size_t)3*HID*HID, out);
}